// Round 8
// baseline (279.926 us; speedup 1.0000x reference)
//
#include <hip/hip_runtime.h>

// Problem constants (from reference): x (4, 4096, 2048) f32; A,B,C,D (2048,) f32.
#define BATCHN 4
#define TLEN   4096
#define DMODEL 2048
#define D4     512        // DMODEL / 4
#define CHUNKS 128
#define LOG2CH 7
#define CLEN   32         // TLEN / CHUNKS
#define NFLAGS (BATCHN * CHUNKS * 2)   // one flag per (b, chunk, d-half)

typedef float f4 __attribute__((ext_vector_type(4)));

// Saturating clamp to +-1e30. NOT +-FLT_MAX: under fast-math (ninf) a
// FLT_MAX-clamp folds to identity and raw inf leaks (rounds 1-3 post-mortem).
// With 1e30 no identity-fold exists; v_min/v_max scrub inf at runtime.
// Healthy channels (|v| < 1e30): exact identity -> exact fp32 semantics.
__device__ __forceinline__ float fin(float v) {
    return fminf(fmaxf(v, -1.0e30f), 1.0e30f);
}
__device__ __forceinline__ f4 fin4(f4 v) {
    f4 r;
    r.x = fin(v.x); r.y = fin(v.y); r.z = fin(v.z); r.w = fin(v.w);
    return r;
}

// Zero the lookback flags (graph-replay-safe: runs before the main kernel
// every call; previous replay leaves flags set).
__global__ __launch_bounds__(256) void ssm_init_flags(unsigned* __restrict__ flags) {
    int i = blockIdx.x * 256 + threadIdx.x;
    if (i < NFLAGS) flags[i] = 0u;
}

// ---------------------------------------------------------------------------
// Single-pass decoupled-lookback scan. Block = (b, chunk c, d-half).
// x chunk lives in REGISTERS across the carry exchange -> x is read from HBM
// exactly once (the R5/R6 two-pass re-read x; y's write-allocate evicted it
// from the memory-side Infinity Cache, so the re-read paid full HBM price).
// Lookback waits only on lower blockIdx (monotone dispatch, rocPRIM-style).
// ---------------------------------------------------------------------------
__global__ __launch_bounds__(256, 2) void ssm_fused(
    const float* __restrict__ x, const float* __restrict__ A,
    const float* __restrict__ B, const float* __restrict__ Cv,
    const float* __restrict__ Dv, float* __restrict__ carry,
    unsigned* __restrict__ flags, float* __restrict__ y) {
    const int bid = blockIdx.x;
    const int half = bid & 1;
    const int rest = bid >> 1;
    const int c = rest & (CHUNKS - 1);
    const int b = rest >> LOG2CH;
    const int d4 = half * 256 + threadIdx.x;

    const f4 a  = ((const f4*)A)[d4];
    const f4 bb = ((const f4*)B)[d4];
    const f4 cc = ((const f4*)Cv)[d4];
    const f4 dd = ((const f4*)Dv)[d4];

    // --- Load this chunk of x into registers (32 independent dwordx4). ---
    const size_t base = (size_t)(b * TLEN + c * CLEN) * D4 + d4;
    const f4* xp = (const f4*)x + base;
    f4 xa[CLEN];
#pragma unroll
    for (int i = 0; i < CLEN; ++i) xa[i] = xp[(size_t)i * D4];

    // --- Local scan from s = 0; publish chunk-final state. ---
    f4 s = {0.f, 0.f, 0.f, 0.f};
#pragma unroll
    for (int i = 0; i < CLEN; ++i) s = fin4(a * s + bb * xa[i]);

    f4* cslot = (f4*)carry + ((size_t)b * CHUNKS + c) * D4 + d4;
    *cslot = s;
    __syncthreads();  // all carry stores of this block issued
    if (threadIdx.x == 0) {
        __threadfence();  // release: carry stores visible device-wide first
        __hip_atomic_store(&flags[bid], 1u, __ATOMIC_RELAXED,
                           __HIP_MEMORY_SCOPE_AGENT);
    }

    // aL = a^CLEN (5 squarings for CLEN=32), finite, >= 0.
    f4 aL = a;
#pragma unroll
    for (int k = 0; k < 5; ++k) aL = fin4(aL * aL);

    // --- Wait for all predecessor chunks (same batch, same d-half). ---
    if (c > 0) {
        if (threadIdx.x == 0) {
            for (int j = 0; j < c; ++j) {
                const unsigned fidx = (unsigned)(((b << LOG2CH) + j) * 2 + half);
                while (__hip_atomic_load(&flags[fidx], __ATOMIC_RELAXED,
                                         __HIP_MEMORY_SCOPE_AGENT) == 0u) {
                    __builtin_amdgcn_s_sleep(8);
                }
            }
        }
        __syncthreads();
        __threadfence();  // acquire side: no carry read moves above this
    }

    // --- Combine predecessor carries: h = sum_j aL^(c-1-j) * carry[j]. ---
    const f4* cp = (const f4*)carry + (size_t)b * CHUNKS * D4 + d4;
    f4 h = {0.f, 0.f, 0.f, 0.f};
    int j = 0;
    for (; j + 8 <= c; j += 8) {
        f4 c0 = cp[(size_t)(j + 0) * D4];
        f4 c1 = cp[(size_t)(j + 1) * D4];
        f4 c2 = cp[(size_t)(j + 2) * D4];
        f4 c3 = cp[(size_t)(j + 3) * D4];
        f4 c4 = cp[(size_t)(j + 4) * D4];
        f4 c5 = cp[(size_t)(j + 5) * D4];
        f4 c6 = cp[(size_t)(j + 6) * D4];
        f4 c7 = cp[(size_t)(j + 7) * D4];
        h = fin4(aL * h + c0);
        h = fin4(aL * h + c1);
        h = fin4(aL * h + c2);
        h = fin4(aL * h + c3);
        h = fin4(aL * h + c4);
        h = fin4(aL * h + c5);
        h = fin4(aL * h + c6);
        h = fin4(aL * h + c7);
    }
    for (; j < c; ++j) h = fin4(aL * h + cp[(size_t)j * D4]);

    // --- Rescan from corrected initial state (x still in regs); write y. ---
    f4* yp = (f4*)y + base;
    f4 s2 = h;
#pragma unroll
    for (int i = 0; i < CLEN; ++i) {
        f4 xi = xa[i];
        s2 = fin4(a * s2 + bb * xi);
        f4 yv = fin4(cc * s2 + dd * xi);
        __builtin_nontemporal_store(yv, yp + (size_t)i * D4);
    }
}

// ---------------------------------------------------------------------------
// Fallback: exact serial scan, one thread per (b,d). Used only if ws_size is
// too small for the chunked path (keeps correctness unconditional).
// ---------------------------------------------------------------------------
__global__ __launch_bounds__(256) void ssm_serial(
    const float* __restrict__ x, const float* __restrict__ A,
    const float* __restrict__ B, const float* __restrict__ Cv,
    const float* __restrict__ Dv, float* __restrict__ y) {
    int g = blockIdx.x * blockDim.x + threadIdx.x;  // [0, BATCHN*DMODEL)
    int d = g & (DMODEL - 1);
    int b = g >> 11;

    float a = A[d], bb = B[d], cc = Cv[d], dd = Dv[d];
    const float* xp = x + (size_t)b * TLEN * DMODEL + d;
    float* yp = y + (size_t)b * TLEN * DMODEL + d;
    float s = 0.f;
    for (int t = 0; t < TLEN; ++t) {
        float xi = xp[(size_t)t * DMODEL];
        s = fin(a * s + bb * xi);
        yp[(size_t)t * DMODEL] = fin(cc * s + dd * xi);
    }
}

extern "C" void kernel_launch(void* const* d_in, const int* in_sizes, int n_in,
                              void* d_out, int out_size, void* d_ws, size_t ws_size,
                              hipStream_t stream) {
    const float* x  = (const float*)d_in[0];
    const float* A  = (const float*)d_in[1];
    const float* B  = (const float*)d_in[2];
    const float* Cv = (const float*)d_in[3];
    const float* Dv = (const float*)d_in[4];
    float* y = (float*)d_out;

    const size_t carry_bytes = (size_t)BATCHN * CHUNKS * DMODEL * sizeof(float);  // 4 MiB
    const size_t need = carry_bytes + NFLAGS * sizeof(unsigned);

    if (ws_size >= need) {
        float* carry = (float*)d_ws;
        unsigned* flags = (unsigned*)((char*)d_ws + carry_bytes);
        const int nblocks = BATCHN * CHUNKS * 2;  // 1024 blocks of 256 threads
        ssm_init_flags<<<(NFLAGS + 255) / 256, 256, 0, stream>>>(flags);
        ssm_fused<<<nblocks, 256, 0, stream>>>(x, A, B, Cv, Dv, carry, flags, y);
    } else {
        const int n2 = BATCHN * DMODEL;
        ssm_serial<<<n2 / 256, 256, 0, stream>>>(x, A, B, Cv, Dv, y);
    }
}

// Round 9
// 134.181 us; speedup vs baseline: 2.0862x; 2.0862x over previous
//
#include <hip/hip_runtime.h>
#include <hip/hip_cooperative_groups.h>

namespace cg = cooperative_groups;

// Problem constants (from reference): x (4, 4096, 2048) f32; A,B,C,D (2048,) f32.
#define BATCHN 4
#define TLEN   4096
#define DMODEL 2048
#define D4     512        // DMODEL / 4
#define CHUNKS 64
#define LOG2CH 6
#define CLEN   64         // TLEN / CHUNKS

typedef float f4 __attribute__((ext_vector_type(4)));

// Saturating clamp to +-1e30. NOT +-FLT_MAX: under fast-math (ninf) a
// FLT_MAX-clamp folds to identity and raw inf leaks (rounds 1-3 post-mortem).
// With 1e30 no identity-fold exists; v_min/v_max scrub inf at runtime.
// Healthy channels (|v| < 1e30): exact identity -> exact fp32 semantics.
__device__ __forceinline__ float fin(float v) {
    return fminf(fmaxf(v, -1.0e30f), 1.0e30f);
}
__device__ __forceinline__ f4 fin4(f4 v) {
    f4 r;
    r.x = fin(v.x); r.y = fin(v.y); r.z = fin(v.z); r.w = fin(v.w);
    return r;
}

// ---------------------------------------------------------------------------
// Cooperative single-kernel scan. Block = (b, chunk c, d-half); 512 blocks.
// Phase A: local scan of the chunk (x read #1, HBM -> populates L3),
//          publish chunk-final carry (2 MiB).
// grid.sync(): ONE release/acquire per block (vs R8's per-flag fence storm
//          that invalidated L2 1000s of times and regressed 3.8x).
// Phase C: combine <=63 predecessor carries (L3-resident, 64 MB total),
//          re-read x (L3 hit: buffer_inv at the sync clears per-XCD L2 only,
//          not the 256 MiB memory-side Infinity Cache), rescan, NT-store y.
// ---------------------------------------------------------------------------
__global__ __launch_bounds__(256, 2) void ssm_coop(
    const float* __restrict__ x, const float* __restrict__ A,
    const float* __restrict__ B, const float* __restrict__ Cv,
    const float* __restrict__ Dv, float* __restrict__ carry,
    float* __restrict__ y) {
    const int bid = blockIdx.x;
    const int half = bid & 1;
    const int rest = bid >> 1;
    const int c = rest & (CHUNKS - 1);
    const int b = rest >> LOG2CH;
    const int d4 = half * 256 + threadIdx.x;

    const f4 a  = ((const f4*)A)[d4];
    const f4 bb = ((const f4*)B)[d4];
    const f4 cc = ((const f4*)Cv)[d4];
    const f4 dd = ((const f4*)Dv)[d4];

    const size_t base = (size_t)(b * TLEN + c * CLEN) * D4 + d4;
    const f4* xp = (const f4*)x + base;

    // --- Phase A: local scan from s = 0; publish chunk-final state. ---
    f4 s = {0.f, 0.f, 0.f, 0.f};
#pragma unroll
    for (int i = 0; i < CLEN; ++i) {
        f4 xi = xp[(size_t)i * D4];
        s = fin4(a * s + bb * xi);
    }
    ((f4*)carry)[((size_t)b * CHUNKS + c) * D4 + d4] = s;

    // --- One grid-wide barrier (carry stores globally visible after). ---
    cg::this_grid().sync();

    // aL = a^CLEN (6 squarings for CLEN=64), kept finite, >= 0.
    f4 aL = a;
#pragma unroll
    for (int k = 0; k < 6; ++k) aL = fin4(aL * aL);

    // --- Combine predecessor carries: h = sum_j aL^(c-1-j) * carry[j]. ---
    const f4* cp = (const f4*)carry + (size_t)b * CHUNKS * D4 + d4;
    f4 h = {0.f, 0.f, 0.f, 0.f};
    int j = 0;
    for (; j + 8 <= c; j += 8) {
        f4 c0 = cp[(size_t)(j + 0) * D4];
        f4 c1 = cp[(size_t)(j + 1) * D4];
        f4 c2 = cp[(size_t)(j + 2) * D4];
        f4 c3 = cp[(size_t)(j + 3) * D4];
        f4 c4 = cp[(size_t)(j + 4) * D4];
        f4 c5 = cp[(size_t)(j + 5) * D4];
        f4 c6 = cp[(size_t)(j + 6) * D4];
        f4 c7 = cp[(size_t)(j + 7) * D4];
        h = fin4(aL * h + c0);
        h = fin4(aL * h + c1);
        h = fin4(aL * h + c2);
        h = fin4(aL * h + c3);
        h = fin4(aL * h + c4);
        h = fin4(aL * h + c5);
        h = fin4(aL * h + c6);
        h = fin4(aL * h + c7);
    }
    for (; j < c; ++j) h = fin4(aL * h + cp[(size_t)j * D4]);

    // --- Phase C: rescan from corrected state (x re-read = L3 hit); write y.
    f4* yp = (f4*)y + base;
    f4 s2 = h;
#pragma unroll
    for (int i = 0; i < CLEN; ++i) {
        f4 xi = xp[(size_t)i * D4];
        s2 = fin4(a * s2 + bb * xi);
        f4 yv = fin4(cc * s2 + dd * xi);
        __builtin_nontemporal_store(yv, yp + (size_t)i * D4);
    }
}

// ---------------------------------------------------------------------------
// Fallback: exact serial scan, one thread per (b,d). Used only if ws_size is
// too small for the chunked path (keeps correctness unconditional).
// ---------------------------------------------------------------------------
__global__ __launch_bounds__(256) void ssm_serial(
    const float* __restrict__ x, const float* __restrict__ A,
    const float* __restrict__ B, const float* __restrict__ Cv,
    const float* __restrict__ Dv, float* __restrict__ y) {
    int g = blockIdx.x * blockDim.x + threadIdx.x;  // [0, BATCHN*DMODEL)
    int d = g & (DMODEL - 1);
    int b = g >> 11;

    float a = A[d], bb = B[d], cc = Cv[d], dd = Dv[d];
    const float* xp = x + (size_t)b * TLEN * DMODEL + d;
    float* yp = y + (size_t)b * TLEN * DMODEL + d;
    float s = 0.f;
    for (int t = 0; t < TLEN; ++t) {
        float xi = xp[(size_t)t * DMODEL];
        s = fin(a * s + bb * xi);
        yp[(size_t)t * DMODEL] = fin(cc * s + dd * xi);
    }
}

extern "C" void kernel_launch(void* const* d_in, const int* in_sizes, int n_in,
                              void* d_out, int out_size, void* d_ws, size_t ws_size,
                              hipStream_t stream) {
    const float* x  = (const float*)d_in[0];
    const float* A  = (const float*)d_in[1];
    const float* B  = (const float*)d_in[2];
    const float* Cv = (const float*)d_in[3];
    const float* Dv = (const float*)d_in[4];
    float* y = (float*)d_out;

    const size_t need = (size_t)BATCHN * CHUNKS * DMODEL * sizeof(float);  // 2 MiB

    if (ws_size >= need) {
        float* carry = (float*)d_ws;
        void* args[] = {(void*)&x, (void*)&A, (void*)&B, (void*)&Cv,
                        (void*)&Dv, (void*)&carry, (void*)&y};
        const int nblocks = BATCHN * CHUNKS * 2;  // 512 blocks of 256 threads
        hipLaunchCooperativeKernel((void*)ssm_coop, dim3(nblocks), dim3(256),
                                   args, 0, stream);
    } else {
        const int n2 = BATCHN * DMODEL;
        ssm_serial<<<n2 / 256, 256, 0, stream>>>(x, A, B, Cv, Dv, y);
    }
}

// Round 10
// 79.573 us; speedup vs baseline: 3.5179x; 1.6863x over previous
//
#include <hip/hip_runtime.h>

// Problem constants (from reference): x (4, 4096, 2048) f32; A,B,C,D (2048,) f32.
#define BATCHN 4
#define TLEN   4096
#define DMODEL 2048
#define D4     512        // DMODEL / 4
#define LOG2D4 9
#define CHUNKS 128
#define LOG2CH 7
#define CLEN   32         // TLEN / CHUNKS

typedef float f4 __attribute__((ext_vector_type(4)));

// Saturating clamp to +-1e30. NOT +-FLT_MAX: under fast-math (ninf) a
// FLT_MAX-clamp folds to identity and raw inf leaks (rounds 1-3 post-mortem).
// With 1e30 no identity-fold exists; v_min/v_max scrub inf at runtime.
// Healthy channels (|v| < 1e30): exact identity -> exact fp32 semantics.
__device__ __forceinline__ float fin(float v) {
    return fminf(fmaxf(v, -1.0e30f), 1.0e30f);
}
__device__ __forceinline__ f4 fin4(f4 v) {
    f4 r;
    r.x = fin(v.x); r.y = fin(v.y); r.z = fin(v.z); r.w = fin(v.w);
    return r;
}

// ---------------------------------------------------------------------------
// Pass 1: per-(b,chunk,d4) local scan from s=0; emit chunk-final state.
// 262144 threads / 1024 blocks; runs at the pure-read roofline (~21 us).
// ---------------------------------------------------------------------------
__global__ __launch_bounds__(256) void ssm_pass1(
    const float* __restrict__ x, const float* __restrict__ A,
    const float* __restrict__ B, float* __restrict__ carry) {
    int g = blockIdx.x * blockDim.x + threadIdx.x;
    int d4 = g & (D4 - 1);
    int rest = g >> LOG2D4;
    int c = rest & (CHUNKS - 1);
    int b = rest >> LOG2CH;

    const f4 a = ((const f4*)A)[d4];
    const f4 bb = ((const f4*)B)[d4];
    const f4* xp = (const f4*)x + (size_t)(b * TLEN + c * CLEN) * D4 + d4;

    f4 s = {0.f, 0.f, 0.f, 0.f};
#pragma unroll
    for (int i = 0; i < CLEN; ++i) {
        f4 xi = xp[(size_t)i * D4];
        s = fin4(a * s + bb * xi);
    }
    ((f4*)carry)[((size_t)b * CHUNKS + c) * D4 + d4] = s;
}

// ---------------------------------------------------------------------------
// Pass 2 (fused combine + rescan), 2 d4-slots per thread:
//  - 2 independent scan chains -> 2x ILP on the dependent FMA/min/max chain
//    and 2 loads + 2 stores in flight per step (better streaming efficiency
//    in this mixed read+write pass, which is the time-dominant one).
//  - x via NON-TEMPORAL loads (no reuse; don't churn L2/L3),
//    y via NON-TEMPORAL stores (no write-allocate pollution).
// R8/R9 lesson: keeping x on-die across carry resolution LOSES (L3-hit reads
// ~2 TB/s < HBM streaming 6.3 TB/s; fences/grid-sync catastrophic), so this
// plain re-read two-pass is the structurally right form; only micro-tune it.
// Block = (b, chunk); 512 blocks of 256 threads.
// ---------------------------------------------------------------------------
__global__ __launch_bounds__(256) void ssm_pass2(
    const float* __restrict__ x, const float* __restrict__ A,
    const float* __restrict__ B, const float* __restrict__ Cv,
    const float* __restrict__ Dv, const float* __restrict__ carry,
    float* __restrict__ y) {
    const int t = threadIdx.x;
    const int c = blockIdx.x & (CHUNKS - 1);
    const int b = blockIdx.x >> LOG2CH;
    const int d4a = t;          // slot 0
    const int d4b = t + 256;    // slot 1

    const f4 a0 = ((const f4*)A)[d4a],  a1 = ((const f4*)A)[d4b];
    const f4 b0 = ((const f4*)B)[d4a],  b1 = ((const f4*)B)[d4b];
    const f4 c0v = ((const f4*)Cv)[d4a], c1v = ((const f4*)Cv)[d4b];
    const f4 d0v = ((const f4*)Dv)[d4a], d1v = ((const f4*)Dv)[d4b];

    // aL = a^CLEN (5 squarings for CLEN=32), kept finite, >= 0.
    f4 aL0 = a0, aL1 = a1;
#pragma unroll
    for (int k = 0; k < 5; ++k) { aL0 = fin4(aL0 * aL0); aL1 = fin4(aL1 * aL1); }

    // Chunk-prefix combine over predecessor carries (block-uniform count),
    // 8-deep unrolled, 16 loads in flight.
    const f4* cp = (const f4*)carry + (size_t)b * CHUNKS * D4;
    f4 h0 = {0.f, 0.f, 0.f, 0.f}, h1 = h0;
    int j = 0;
    for (; j + 8 <= c; j += 8) {
#pragma unroll
        for (int u = 0; u < 8; ++u) {
            f4 ca = cp[(size_t)(j + u) * D4 + d4a];
            f4 cb = cp[(size_t)(j + u) * D4 + d4b];
            h0 = fin4(aL0 * h0 + ca);
            h1 = fin4(aL1 * h1 + cb);
        }
    }
    for (; j < c; ++j) {
        h0 = fin4(aL0 * h0 + cp[(size_t)j * D4 + d4a]);
        h1 = fin4(aL1 * h1 + cp[(size_t)j * D4 + d4b]);
    }

    // Rescan chunk from corrected initial state; NT load x, NT store y.
    const size_t base = (size_t)(b * TLEN + c * CLEN) * D4;
    const f4* xp = (const f4*)x + base;
    f4* yp = (f4*)y + base;
    f4 s0 = h0, s1 = h1;
#pragma unroll
    for (int i = 0; i < CLEN; ++i) {
        const size_t row = (size_t)i * D4;
        f4 xi0 = __builtin_nontemporal_load(xp + row + d4a);
        f4 xi1 = __builtin_nontemporal_load(xp + row + d4b);
        s0 = fin4(a0 * s0 + b0 * xi0);
        s1 = fin4(a1 * s1 + b1 * xi1);
        f4 y0 = fin4(c0v * s0 + d0v * xi0);
        f4 y1 = fin4(c1v * s1 + d1v * xi1);
        __builtin_nontemporal_store(y0, yp + row + d4a);
        __builtin_nontemporal_store(y1, yp + row + d4b);
    }
}

// ---------------------------------------------------------------------------
// Fallback: exact serial scan, one thread per (b,d). Used only if ws_size is
// too small for the chunked path (keeps correctness unconditional).
// ---------------------------------------------------------------------------
__global__ __launch_bounds__(256) void ssm_serial(
    const float* __restrict__ x, const float* __restrict__ A,
    const float* __restrict__ B, const float* __restrict__ Cv,
    const float* __restrict__ Dv, float* __restrict__ y) {
    int g = blockIdx.x * blockDim.x + threadIdx.x;  // [0, BATCHN*DMODEL)
    int d = g & (DMODEL - 1);
    int b = g >> 11;

    float a = A[d], bb = B[d], cc = Cv[d], dd = Dv[d];
    const float* xp = x + (size_t)b * TLEN * DMODEL + d;
    float* yp = y + (size_t)b * TLEN * DMODEL + d;
    float s = 0.f;
    for (int t = 0; t < TLEN; ++t) {
        float xi = xp[(size_t)t * DMODEL];
        s = fin(a * s + bb * xi);
        yp[(size_t)t * DMODEL] = fin(cc * s + dd * xi);
    }
}

extern "C" void kernel_launch(void* const* d_in, const int* in_sizes, int n_in,
                              void* d_out, int out_size, void* d_ws, size_t ws_size,
                              hipStream_t stream) {
    const float* x  = (const float*)d_in[0];
    const float* A  = (const float*)d_in[1];
    const float* B  = (const float*)d_in[2];
    const float* Cv = (const float*)d_in[3];
    const float* Dv = (const float*)d_in[4];
    float* y = (float*)d_out;

    const size_t need = (size_t)BATCHN * CHUNKS * DMODEL * sizeof(float);  // 4 MiB

    if (ws_size >= need) {
        float* carry = (float*)d_ws;
        const int n1 = BATCHN * CHUNKS * D4;  // 262144 threads for pass1
        ssm_pass1<<<n1 / 256, 256, 0, stream>>>(x, A, B, carry);
        const int n2blocks = BATCHN * CHUNKS;  // 512 blocks for pass2
        ssm_pass2<<<n2blocks, 256, 0, stream>>>(x, A, B, Cv, Dv, carry, y);
    } else {
        const int n2 = BATCHN * DMODEL;
        ssm_serial<<<n2 / 256, 256, 0, stream>>>(x, A, B, Cv, Dv, y);
    }
}

// Round 11
// 79.316 us; speedup vs baseline: 3.5293x; 1.0032x over previous
//
#include <hip/hip_runtime.h>

// Problem constants (from reference): x (4, 4096, 2048) f32; A,B,C,D (2048,) f32.
#define BATCHN 4
#define TLEN   4096
#define DMODEL 2048
#define D4     512        // DMODEL / 4
#define LOG2D4 9
#define CHUNKS 128
#define LOG2CH 7
#define CLEN   32         // TLEN / CHUNKS

typedef float f4 __attribute__((ext_vector_type(4)));

// Saturating clamp to +-1e30. NOT +-FLT_MAX: under fast-math (ninf) a
// FLT_MAX-clamp folds to identity and raw inf leaks (rounds 1-3 post-mortem).
// With 1e30 no identity-fold exists; v_min/v_max scrub inf at runtime.
// Healthy channels (|v| < 1e30): exact identity -> exact fp32 semantics.
__device__ __forceinline__ float fin(float v) {
    return fminf(fmaxf(v, -1.0e30f), 1.0e30f);
}
__device__ __forceinline__ f4 fin4(f4 v) {
    f4 r;
    r.x = fin(v.x); r.y = fin(v.y); r.z = fin(v.z); r.w = fin(v.w);
    return r;
}

// ---------------------------------------------------------------------------
// Pass 1: per-(b,chunk,d4) local scan from s=0; emit chunk-final state.
// 262144 threads / 1024 blocks; runs at the pure-read roofline (~21 us).
// Plain (cached) loads and stores: carries are re-read by pass1b.
// ---------------------------------------------------------------------------
__global__ __launch_bounds__(256) void ssm_pass1(
    const float* __restrict__ x, const float* __restrict__ A,
    const float* __restrict__ B, float* __restrict__ carry) {
    int g = blockIdx.x * blockDim.x + threadIdx.x;
    int d4 = g & (D4 - 1);
    int rest = g >> LOG2D4;
    int c = rest & (CHUNKS - 1);
    int b = rest >> LOG2CH;

    const f4 a = ((const f4*)A)[d4];
    const f4 bb = ((const f4*)B)[d4];
    const f4* xp = (const f4*)x + (size_t)(b * TLEN + c * CLEN) * D4 + d4;

    f4 s = {0.f, 0.f, 0.f, 0.f};
#pragma unroll
    for (int i = 0; i < CLEN; ++i) {
        f4 xi = xp[(size_t)i * D4];
        s = fin4(a * s + bb * xi);
    }
    ((f4*)carry)[((size_t)b * CHUNKS + c) * D4 + d4] = s;
}

// ---------------------------------------------------------------------------
// Pass 1b: chunk-prefix combine, one thread per (b,d4).
//   hin[c] = state at the START of chunk c:  h=0; hin[c]=h; h = aL*h + carry[c]
// 2048 threads / 8 blocks. The h-chain is serial but the carry loads are
// independent -> 8-deep load-ahead pipelines the latency (~4 us total).
// This kernel REPLACES pass2's per-block combine preamble, deleting the
// 266 MB of redundant on-die carry re-reads (B*D4*16B*CH^2/2) that R5/R6
// pass2 performed concurrently with its HBM streams.
// ---------------------------------------------------------------------------
__global__ __launch_bounds__(256) void ssm_pass1b(
    const float* __restrict__ A, const float* __restrict__ carry,
    float* __restrict__ hin) {
    int t = blockIdx.x * blockDim.x + threadIdx.x;  // [0, BATCHN*D4)
    int d4 = t & (D4 - 1);
    int b = t >> LOG2D4;

    const f4 a = ((const f4*)A)[d4];
    f4 aL = a;
#pragma unroll
    for (int k = 0; k < 5; ++k) aL = fin4(aL * aL);  // a^CLEN, finite, >=0

    const f4* cp = (const f4*)carry + (size_t)b * CHUNKS * D4 + d4;
    f4* hp = (f4*)hin + (size_t)b * CHUNKS * D4 + d4;

    f4 h = {0.f, 0.f, 0.f, 0.f};
    for (int c0 = 0; c0 < CHUNKS; c0 += 8) {
        f4 k0 = cp[(size_t)(c0 + 0) * D4];
        f4 k1 = cp[(size_t)(c0 + 1) * D4];
        f4 k2 = cp[(size_t)(c0 + 2) * D4];
        f4 k3 = cp[(size_t)(c0 + 3) * D4];
        f4 k4 = cp[(size_t)(c0 + 4) * D4];
        f4 k5 = cp[(size_t)(c0 + 5) * D4];
        f4 k6 = cp[(size_t)(c0 + 6) * D4];
        f4 k7 = cp[(size_t)(c0 + 7) * D4];
        hp[(size_t)(c0 + 0) * D4] = h; h = fin4(aL * h + k0);
        hp[(size_t)(c0 + 1) * D4] = h; h = fin4(aL * h + k1);
        hp[(size_t)(c0 + 2) * D4] = h; h = fin4(aL * h + k2);
        hp[(size_t)(c0 + 3) * D4] = h; h = fin4(aL * h + k3);
        hp[(size_t)(c0 + 4) * D4] = h; h = fin4(aL * h + k4);
        hp[(size_t)(c0 + 5) * D4] = h; h = fin4(aL * h + k5);
        hp[(size_t)(c0 + 6) * D4] = h; h = fin4(aL * h + k6);
        hp[(size_t)(c0 + 7) * D4] = h; h = fin4(aL * h + k7);
    }
}

// ---------------------------------------------------------------------------
// Pass 3: per-(b,chunk,d4) rescan from hin[chunk]; write y.
// Starts streaming immediately (no combine preamble). Plain x loads
// (NT x-loads regressed in R10); NT y-stores (no write-allocate pollution).
// ---------------------------------------------------------------------------
__global__ __launch_bounds__(256) void ssm_pass3(
    const float* __restrict__ x, const float* __restrict__ A,
    const float* __restrict__ B, const float* __restrict__ Cv,
    const float* __restrict__ Dv, const float* __restrict__ hin,
    float* __restrict__ y) {
    int g = blockIdx.x * blockDim.x + threadIdx.x;
    int d4 = g & (D4 - 1);
    int rest = g >> LOG2D4;
    int c = rest & (CHUNKS - 1);
    int b = rest >> LOG2CH;

    const f4 a = ((const f4*)A)[d4];
    const f4 bb = ((const f4*)B)[d4];
    const f4 cc = ((const f4*)Cv)[d4];
    const f4 dd = ((const f4*)Dv)[d4];

    const size_t base = (size_t)(b * TLEN + c * CLEN) * D4 + d4;
    const f4* xp = (const f4*)x + base;
    f4* yp = (f4*)y + base;

    f4 s = ((const f4*)hin)[((size_t)b * CHUNKS + c) * D4 + d4];
#pragma unroll
    for (int i = 0; i < CLEN; ++i) {
        f4 xi = xp[(size_t)i * D4];
        s = fin4(a * s + bb * xi);
        f4 yv = fin4(cc * s + dd * xi);
        __builtin_nontemporal_store(yv, yp + (size_t)i * D4);
    }
}

// ---------------------------------------------------------------------------
// Fallback: exact serial scan, one thread per (b,d). Used only if ws_size is
// too small for the chunked path (keeps correctness unconditional).
// ---------------------------------------------------------------------------
__global__ __launch_bounds__(256) void ssm_serial(
    const float* __restrict__ x, const float* __restrict__ A,
    const float* __restrict__ B, const float* __restrict__ Cv,
    const float* __restrict__ Dv, float* __restrict__ y) {
    int g = blockIdx.x * blockDim.x + threadIdx.x;  // [0, BATCHN*DMODEL)
    int d = g & (DMODEL - 1);
    int b = g >> 11;

    float a = A[d], bb = B[d], cc = Cv[d], dd = Dv[d];
    const float* xp = x + (size_t)b * TLEN * DMODEL + d;
    float* yp = y + (size_t)b * TLEN * DMODEL + d;
    float s = 0.f;
    for (int t = 0; t < TLEN; ++t) {
        float xi = xp[(size_t)t * DMODEL];
        s = fin(a * s + bb * xi);
        yp[(size_t)t * DMODEL] = fin(cc * s + dd * xi);
    }
}

extern "C" void kernel_launch(void* const* d_in, const int* in_sizes, int n_in,
                              void* d_out, int out_size, void* d_ws, size_t ws_size,
                              hipStream_t stream) {
    const float* x  = (const float*)d_in[0];
    const float* A  = (const float*)d_in[1];
    const float* B  = (const float*)d_in[2];
    const float* Cv = (const float*)d_in[3];
    const float* Dv = (const float*)d_in[4];
    float* y = (float*)d_out;

    const size_t seg = (size_t)BATCHN * CHUNKS * DMODEL * sizeof(float);  // 4 MiB
    const size_t need = 2 * seg;  // carry + hin

    if (ws_size >= need) {
        float* carry = (float*)d_ws;
        float* hin = (float*)((char*)d_ws + seg);
        const int n1 = BATCHN * CHUNKS * D4;   // 262144 threads
        const int nb = BATCHN * D4;            // 2048 threads
        ssm_pass1<<<n1 / 256, 256, 0, stream>>>(x, A, B, carry);
        ssm_pass1b<<<nb / 256, 256, 0, stream>>>(A, carry, hin);
        ssm_pass3<<<n1 / 256, 256, 0, stream>>>(x, A, B, Cv, Dv, hin, y);
    } else {
        const int n2 = BATCHN * DMODEL;
        ssm_serial<<<n2 / 256, 256, 0, stream>>>(x, A, B, Cv, Dv, y);
    }
}

// Round 12
// 73.222 us; speedup vs baseline: 3.8230x; 1.0832x over previous
//
#include <hip/hip_runtime.h>

// Problem constants (from reference): x (4, 4096, 2048) f32; A,B,C,D (2048,) f32.
#define BATCHN 4
#define TLEN   4096
#define DMODEL 2048
#define D4     512        // DMODEL / 4
#define LOG2D4 9
#define CHUNKS 128
#define LOG2CH 7
#define CLEN   32         // TLEN / CHUNKS
#define PF     8          // x rows prefetched into regs before the combine

typedef float f4 __attribute__((ext_vector_type(4)));

// Saturating clamp to +-1e30. NOT +-FLT_MAX: under fast-math (ninf) a
// FLT_MAX-clamp folds to identity and raw inf leaks (rounds 1-3 post-mortem).
// With 1e30 no identity-fold exists; v_min/v_max scrub inf at runtime.
// Healthy channels (|v| < 1e30): exact identity -> exact fp32 semantics.
__device__ __forceinline__ float fin(float v) {
    return fminf(fmaxf(v, -1.0e30f), 1.0e30f);
}
__device__ __forceinline__ f4 fin4(f4 v) {
    f4 r;
    r.x = fin(v.x); r.y = fin(v.y); r.z = fin(v.z); r.w = fin(v.w);
    return r;
}

// ---------------------------------------------------------------------------
// Pass 1: per-(b,chunk,d4) local scan from s=0; emit chunk-final state.
// 262144 threads / 1024 blocks (4/CU); runs at the pure-read roofline.
// (Unchanged from the 74.1 us R6 baseline.)
// ---------------------------------------------------------------------------
__global__ __launch_bounds__(256) void ssm_pass1(
    const float* __restrict__ x, const float* __restrict__ A,
    const float* __restrict__ B, float* __restrict__ carry) {
    int g = blockIdx.x * blockDim.x + threadIdx.x;
    int d4 = g & (D4 - 1);
    int rest = g >> LOG2D4;
    int c = rest & (CHUNKS - 1);
    int b = rest >> LOG2CH;

    const f4 a = ((const f4*)A)[d4];
    const f4 bb = ((const f4*)B)[d4];
    const f4* xp = (const f4*)x + (size_t)(b * TLEN + c * CLEN) * D4 + d4;

    f4 s = {0.f, 0.f, 0.f, 0.f};
#pragma unroll
    for (int i = 0; i < CLEN; ++i) {
        f4 xi = xp[(size_t)i * D4];
        s = fin4(a * s + bb * xi);
    }
    ((f4*)carry)[((size_t)b * CHUNKS + c) * D4 + d4] = s;
}

// ---------------------------------------------------------------------------
// Pass 2 (fused combine + rescan), R6 base + x-PREFETCH:
// The first PF x-rows are loaded into registers BEFORE the combine preamble,
// so the stream's initial HBM latency is paid underneath the combine's
// dependent L2/L3 chain instead of after it (T14 issue-early/consume-late).
// Combine numerics identical to the proven R6 kernel. Plain x loads
// (NT x-loads regressed in R10); NT y-stores (no write-allocate pollution).
// 1024 blocks of 256 threads (4/CU).
// ---------------------------------------------------------------------------
__global__ __launch_bounds__(256) void ssm_pass2(
    const float* __restrict__ x, const float* __restrict__ A,
    const float* __restrict__ B, const float* __restrict__ Cv,
    const float* __restrict__ Dv, const float* __restrict__ carry,
    float* __restrict__ y) {
    int g = blockIdx.x * blockDim.x + threadIdx.x;
    int d4 = g & (D4 - 1);
    int rest = g >> LOG2D4;
    int c = rest & (CHUNKS - 1);
    int b = rest >> LOG2CH;

    const f4 a  = ((const f4*)A)[d4];
    const f4 bb = ((const f4*)B)[d4];
    const f4 cc = ((const f4*)Cv)[d4];
    const f4 dd = ((const f4*)Dv)[d4];

    const size_t base = (size_t)(b * TLEN + c * CLEN) * D4 + d4;
    const f4* xp = (const f4*)x + base;
    f4* yp = (f4*)y + base;

    // --- Issue the first PF x-row loads NOW; consumed after the combine. ---
    f4 xa[PF];
#pragma unroll
    for (int i = 0; i < PF; ++i) xa[i] = xp[(size_t)i * D4];

    // aL = a^CLEN (5 squarings for CLEN=32), kept finite, >= 0.
    f4 aL = a;
#pragma unroll
    for (int k = 0; k < 5; ++k) aL = fin4(aL * aL);

    // Chunk-prefix combine over predecessor carries (block-uniform count),
    // 8-deep unrolled so 8 carry loads are in flight per dependent group.
    const f4* cp = (const f4*)carry + (size_t)b * CHUNKS * D4 + d4;
    f4 h = {0.f, 0.f, 0.f, 0.f};
    int j = 0;
    for (; j + 8 <= c; j += 8) {
        f4 c0 = cp[(size_t)(j + 0) * D4];
        f4 c1 = cp[(size_t)(j + 1) * D4];
        f4 c2 = cp[(size_t)(j + 2) * D4];
        f4 c3 = cp[(size_t)(j + 3) * D4];
        f4 c4 = cp[(size_t)(j + 4) * D4];
        f4 c5 = cp[(size_t)(j + 5) * D4];
        f4 c6 = cp[(size_t)(j + 6) * D4];
        f4 c7 = cp[(size_t)(j + 7) * D4];
        h = fin4(aL * h + c0);
        h = fin4(aL * h + c1);
        h = fin4(aL * h + c2);
        h = fin4(aL * h + c3);
        h = fin4(aL * h + c4);
        h = fin4(aL * h + c5);
        h = fin4(aL * h + c6);
        h = fin4(aL * h + c7);
    }
    for (; j < c; ++j) h = fin4(aL * h + cp[(size_t)j * D4]);

    // --- Rescan: first PF rows from registers, rest streamed. NT y-store. ---
    f4 s = h;
#pragma unroll
    for (int i = 0; i < PF; ++i) {
        f4 xi = xa[i];
        s = fin4(a * s + bb * xi);
        f4 yv = fin4(cc * s + dd * xi);
        __builtin_nontemporal_store(yv, yp + (size_t)i * D4);
    }
#pragma unroll
    for (int i = PF; i < CLEN; ++i) {
        f4 xi = xp[(size_t)i * D4];
        s = fin4(a * s + bb * xi);
        f4 yv = fin4(cc * s + dd * xi);
        __builtin_nontemporal_store(yv, yp + (size_t)i * D4);
    }
}

// ---------------------------------------------------------------------------
// Fallback: exact serial scan, one thread per (b,d). Used only if ws_size is
// too small for the chunked path (keeps correctness unconditional).
// ---------------------------------------------------------------------------
__global__ __launch_bounds__(256) void ssm_serial(
    const float* __restrict__ x, const float* __restrict__ A,
    const float* __restrict__ B, const float* __restrict__ Cv,
    const float* __restrict__ Dv, float* __restrict__ y) {
    int g = blockIdx.x * blockDim.x + threadIdx.x;  // [0, BATCHN*DMODEL)
    int d = g & (DMODEL - 1);
    int b = g >> 11;

    float a = A[d], bb = B[d], cc = Cv[d], dd = Dv[d];
    const float* xp = x + (size_t)b * TLEN * DMODEL + d;
    float* yp = y + (size_t)b * TLEN * DMODEL + d;
    float s = 0.f;
    for (int t = 0; t < TLEN; ++t) {
        float xi = xp[(size_t)t * DMODEL];
        s = fin(a * s + bb * xi);
        yp[(size_t)t * DMODEL] = fin(cc * s + dd * xi);
    }
}

extern "C" void kernel_launch(void* const* d_in, const int* in_sizes, int n_in,
                              void* d_out, int out_size, void* d_ws, size_t ws_size,
                              hipStream_t stream) {
    const float* x  = (const float*)d_in[0];
    const float* A  = (const float*)d_in[1];
    const float* B  = (const float*)d_in[2];
    const float* Cv = (const float*)d_in[3];
    const float* Dv = (const float*)d_in[4];
    float* y = (float*)d_out;

    const size_t need = (size_t)BATCHN * CHUNKS * DMODEL * sizeof(float);  // 4 MiB

    if (ws_size >= need) {
        float* carry = (float*)d_ws;
        const int n1 = BATCHN * CHUNKS * D4;  // 262144 threads, 1024 blocks
        ssm_pass1<<<n1 / 256, 256, 0, stream>>>(x, A, B, carry);
        ssm_pass2<<<n1 / 256, 256, 0, stream>>>(x, A, B, Cv, Dv, carry, y);
    } else {
        const int n2 = BATCHN * DMODEL;
        ssm_serial<<<n2 / 256, 256, 0, stream>>>(x, A, B, Cv, Dv, y);
    }
}

// Round 13
// 56.974 us; speedup vs baseline: 4.9132x; 1.2852x over previous
//
#include <hip/hip_runtime.h>

// x (4, 4096, 2048) f32; A,B,C,D (2048,) f32.  Single-kernel block-owned scan:
// each block owns (batch b, 8 f4-channels, ALL T) -> x read ONCE, y written
// once (268 MB total vs two-pass 402 MB). No cross-block sync (R8/R9 lesson).
#define BATCHN  4
#define TLEN    4096
#define D4      512       // DMODEL/4 in f4 units
#define DG      8         // f4 channels per block
#define NDG     64        // D4/DG
#define THREADS 512
#define TTILE   512       // rows per LDS tile
#define NTILE   8         // TLEN/TTILE
#define NSUB    64        // THREADS/DG  (t-subchunks per tile)
#define TSUB    8         // TTILE/NSUB  (rows per thread)

typedef float f4 __attribute__((ext_vector_type(4)));

// Saturating clamp to +-1e30 (survives fast-math; scrubs inf; identity for
// healthy channels). Proven in R4-R12.
__device__ __forceinline__ float fin(float v) {
    return fminf(fmaxf(v, -1.0e30f), 1.0e30f);
}
__device__ __forceinline__ f4 fin4(f4 v) {
    f4 r;
    r.x = fin(v.x); r.y = fin(v.y); r.z = fin(v.z); r.w = fin(v.w);
    return r;
}

// Raw barrier: lgkmcnt(0) for LDS visibility, NO vmcnt drain (a __syncthreads
// would wait vmcnt(0) and kill the in-flight next-tile staged loads — the
// whole point of reg-staging). "memory" clobbers pin global loads/stores at
// their issue points across phases.
#define BAR() do { asm volatile("s_waitcnt lgkmcnt(0)" ::: "memory"); \
                   __builtin_amdgcn_s_barrier();                       \
                   asm volatile("" ::: "memory"); } while (0)

// LDS layout: tile[row][swz(col,row)] with swz = (col + (row>>3)) & 7.
// Breaks the 128B-period bank degeneracy of the scan-phase column reads
// (G4 / T2): per-wave b128 reads spread over all 8 16B slots of the period.
__device__ __forceinline__ int swz(int row, int col) {
    return row * DG + ((col + (row >> 3)) & 7);
}

__global__ __launch_bounds__(THREADS, 1) void ssm_onepass(
    const float* __restrict__ xg, const float* __restrict__ A,
    const float* __restrict__ B, const float* __restrict__ Cv,
    const float* __restrict__ Dv, float* __restrict__ yg) {
    __shared__ f4 tile[TTILE * DG];   // 64 KiB x-tile, overwritten by y
    __shared__ f4 pfx[NSUB * DG];     // 8 KiB local-carry / exclusive-prefix

    const int tid = threadIdx.x;
    const int dg  = blockIdx.x & (NDG - 1);
    const int b   = blockIdx.x >> 6;
    const int ch  = tid & (DG - 1);   // my f4 channel within the group
    const int sub = tid >> 3;         // my t-subchunk (0..63)

    const int d4 = dg * DG + ch;
    const f4 a  = ((const f4*)A)[d4];
    const f4 bb = ((const f4*)B)[d4];
    const f4 cc = ((const f4*)Cv)[d4];
    const f4 dd = ((const f4*)Dv)[d4];
    const f4 a2 = fin4(a * a), a4 = fin4(a2 * a2), a8 = fin4(a4 * a4);

    // Running block-level state; meaningful only in threads 0..7 (ch == tid).
    f4 S = {0.f, 0.f, 0.f, 0.f};

    const size_t slice = (size_t)b * TLEN * D4 + (size_t)dg * DG;  // f4 units
    const f4* xbase = (const f4*)xg + slice;
    f4* ybase = (f4*)yg + slice;

    // ---- Prologue: load tile 0 (coalesced 128B groups) -> LDS swizzled. ----
    {
        f4 r[TSUB];
#pragma unroll
        for (int q = 0; q < TSUB; ++q) {
            int flat = q * THREADS + tid;            // 0..4095 over (row,col)
            r[q] = xbase[(size_t)(flat >> 3) * D4 + (flat & 7)];
        }
#pragma unroll
        for (int q = 0; q < TSUB; ++q) {
            int flat = q * THREADS + tid;
            tile[swz(flat >> 3, flat & 7)] = r[q];
        }
    }
    BAR();

    for (int t = 0; t < NTILE; ++t) {
        // (A) stage next tile into regs NOW; consumed at (G) after compute.
        f4 xnext[TSUB];
        if (t + 1 < NTILE) {
#pragma unroll
            for (int q = 0; q < TSUB; ++q) {
                int flat = q * THREADS + tid;
                xnext[q] = xbase[(size_t)((t + 1) * TTILE + (flat >> 3)) * D4
                                 + (flat & 7)];
            }
        }

        // (B) local scan of my 8 rows (channel ch, rows sub*8..sub*8+7).
        f4 xcur[TSUB];
        {
            const int r0 = sub * TSUB;
#pragma unroll
            for (int i = 0; i < TSUB; ++i)
                xcur[i] = tile[swz(r0 + i, ch)];
            f4 v = {0.f, 0.f, 0.f, 0.f};
#pragma unroll
            for (int i = 0; i < TSUB; ++i) v = fin4(a * v + bb * xcur[i]);
            pfx[sub * DG + ch] = v;   // local carry of my subchunk
        }
        BAR();

        // (D) exclusive-prefix combine: thread ch (<8) walks the 64 subchunk
        // carries of its channel; 8-deep load-ahead keeps the dep chain VALU-
        // bound (~12 cy/step). Writes the subchunk START state in place.
        if (tid < DG) {
            for (int s0 = 0; s0 < NSUB; s0 += 8) {
                f4 v0 = pfx[(s0 + 0) * DG + tid];
                f4 v1 = pfx[(s0 + 1) * DG + tid];
                f4 v2 = pfx[(s0 + 2) * DG + tid];
                f4 v3 = pfx[(s0 + 3) * DG + tid];
                f4 v4 = pfx[(s0 + 4) * DG + tid];
                f4 v5 = pfx[(s0 + 5) * DG + tid];
                f4 v6 = pfx[(s0 + 6) * DG + tid];
                f4 v7 = pfx[(s0 + 7) * DG + tid];
                pfx[(s0 + 0) * DG + tid] = S; S = fin4(a8 * S + v0);
                pfx[(s0 + 1) * DG + tid] = S; S = fin4(a8 * S + v1);
                pfx[(s0 + 2) * DG + tid] = S; S = fin4(a8 * S + v2);
                pfx[(s0 + 3) * DG + tid] = S; S = fin4(a8 * S + v3);
                pfx[(s0 + 4) * DG + tid] = S; S = fin4(a8 * S + v4);
                pfx[(s0 + 5) * DG + tid] = S; S = fin4(a8 * S + v5);
                pfx[(s0 + 6) * DG + tid] = S; S = fin4(a8 * S + v6);
                pfx[(s0 + 7) * DG + tid] = S; S = fin4(a8 * S + v7);
            }
        }
        BAR();

        // (E) rescan my rows from the corrected start state; y overwrites
        // the x-tile in LDS (x is live in xcur regs).
        {
            f4 s = pfx[sub * DG + ch];
            const int r0 = sub * TSUB;
#pragma unroll
            for (int i = 0; i < TSUB; ++i) {
                f4 xi = xcur[i];
                s = fin4(a * s + bb * xi);
                tile[swz(r0 + i, ch)] = fin4(cc * s + dd * xi);
            }
        }
        BAR();

        // (F) cooperative y store (coalesced 128B groups, non-temporal).
#pragma unroll
        for (int q = 0; q < TSUB; ++q) {
            int flat = q * THREADS + tid;
            f4 yv = tile[swz(flat >> 3, flat & 7)];
            __builtin_nontemporal_store(
                yv, ybase + (size_t)(t * TTILE + (flat >> 3)) * D4 + (flat & 7));
        }

        // (G) commit staged x into the tile (compiler inserts the precise
        // vmcnt wait for xnext here; barrier first so (F)'s LDS reads retire).
        if (t + 1 < NTILE) {
            BAR();
#pragma unroll
            for (int q = 0; q < TSUB; ++q) {
                int flat = q * THREADS + tid;
                tile[swz(flat >> 3, flat & 7)] = xnext[q];
            }
            BAR();
        }
    }
}

extern "C" void kernel_launch(void* const* d_in, const int* in_sizes, int n_in,
                              void* d_out, int out_size, void* d_ws, size_t ws_size,
                              hipStream_t stream) {
    const float* x  = (const float*)d_in[0];
    const float* A  = (const float*)d_in[1];
    const float* B  = (const float*)d_in[2];
    const float* Cv = (const float*)d_in[3];
    const float* Dv = (const float*)d_in[4];
    float* y = (float*)d_out;

    const int nblocks = BATCHN * NDG;  // 256 blocks x 512 threads
    ssm_onepass<<<nblocks, THREADS, 0, stream>>>(x, A, B, Cv, Dv, y);
}

// Round 14
// 56.079 us; speedup vs baseline: 4.9916x; 1.0160x over previous
//
#include <hip/hip_runtime.h>

// x (4, 4096, 2048) f32; A,B,C,D (2048,) f32.  Single-kernel block-owned scan:
// each block owns (batch b, 8 f4-channels, ALL T). x read ONCE via
// double-buffered global_load_lds DMA (counted vmcnt, never drained to 0),
// y written once. No cross-block sync (R8/R9 lesson).
#define BATCHN  4
#define TLEN    4096
#define D4      512       // DMODEL/4 in f4 units
#define DG      8         // f4 channels per block
#define NDG     64        // D4/DG
#define THREADS 512
#define TTILE   512       // rows per LDS tile
#define NTILE   8         // TLEN/TTILE
#define NSUB    64        // THREADS/DG  (t-subchunks per tile)
#define TSUB    8         // TTILE/NSUB  (rows per thread)
#define TILE_F4 (TTILE * DG)  // 4096 f4 = 64 KiB per buffer

typedef float f4 __attribute__((ext_vector_type(4)));

// Saturating clamp to +-1e30 (survives fast-math; scrubs inf; identity for
// healthy channels). Proven R4-R13.
__device__ __forceinline__ float fin(float v) {
    return fminf(fmaxf(v, -1.0e30f), 1.0e30f);
}
__device__ __forceinline__ f4 fin4(f4 v) {
    f4 r;
    r.x = fin(v.x); r.y = fin(v.y); r.z = fin(v.z); r.w = fin(v.w);
    return r;
}

// Raw barrier: lgkmcnt(0) for LDS visibility, NO vmcnt drain (keeps the
// DMA staging loads in flight across phases). "memory" clobbers pin
// global/LDS ops at their issue points.
#define BAR() do { asm volatile("s_waitcnt lgkmcnt(0)" ::: "memory"); \
                   __builtin_amdgcn_s_barrier();                       \
                   asm volatile("" ::: "memory"); } while (0)

// LDS slot for logical (row, col): linear-in-lane DMA order, column rotated
// by (row>>3)&7 to break the 128B-period bank degeneracy of column reads.
// Rule #21 compliant: linear LDS dest + inverse-swizzled global SOURCE +
// swizzled READ. Inverse: slot s holds x(row = s>>3, col = ((s&7)-(s>>6))&7).
__device__ __forceinline__ int swz(int row, int col) {
    return row * DG + ((col + (row >> 3)) & 7);
}

__global__ __launch_bounds__(THREADS, 1) void ssm_onepass(
    const float* __restrict__ xg, const float* __restrict__ A,
    const float* __restrict__ B, const float* __restrict__ Cv,
    const float* __restrict__ Dv, float* __restrict__ yg) {
    __shared__ f4 tile[2 * TILE_F4];  // 128 KiB double buffer
    __shared__ f4 pfx[NSUB * DG];     // 8 KiB local-carry / exclusive-prefix

    const int tid  = threadIdx.x;
    const int lane = tid & 63;
    const int wid  = tid >> 6;
    const int dg   = blockIdx.x & (NDG - 1);
    const int b    = blockIdx.x >> 6;
    const int ch   = tid & (DG - 1);  // my f4 channel within the group
    const int sub  = tid >> 3;        // my t-subchunk (0..63)

    const int d4 = dg * DG + ch;
    const f4 a  = ((const f4*)A)[d4];
    const f4 bb = ((const f4*)B)[d4];
    const f4 cc = ((const f4*)Cv)[d4];
    const f4 dd = ((const f4*)Dv)[d4];
    const f4 a2 = fin4(a * a), a4 = fin4(a2 * a2), a8 = fin4(a4 * a4);

    f4 S = {0.f, 0.f, 0.f, 0.f};  // running state (threads 0..7 only)

    const size_t slice = (size_t)b * TLEN * D4 + (size_t)dg * DG;  // f4 units
    const f4* xbase = (const f4*)xg + slice;
    f4* ybase = (f4*)yg + slice;

    // Per-thread DMA descriptor: my wave covers slots q*512+wid*64+[0,64).
    // My lane's slot: row within tile + inverse-swizzled global column.
    int g_row[TSUB], g_col[TSUB];
#pragma unroll
    for (int q = 0; q < TSUB; ++q) {
        int s = q * THREADS + wid * 64 + lane;
        g_row[q] = s >> 3;
        g_col[q] = ((s & 7) - (s >> 6)) & 7;
    }

    // Issue the 8 DMA loads for tile t into buffer bufi. LDS dest is
    // wave-uniform base + lane*16 (m104); global source is per-lane.
#define STAGE(t_, bufi_) do {                                                  \
        const f4* gq;                                                          \
        f4* lq;                                                                \
        _Pragma("unroll")                                                      \
        for (int q = 0; q < TSUB; ++q) {                                       \
            gq = xbase + (size_t)((t_) * TTILE + g_row[q]) * D4 + g_col[q];    \
            lq = &tile[(bufi_) * TILE_F4 + q * THREADS + wid * 64];            \
            __builtin_amdgcn_global_load_lds(                                  \
                (const __attribute__((address_space(1))) void*)gq,             \
                (__attribute__((address_space(3))) void*)lq, 16, 0, 0);        \
        }                                                                      \
    } while (0)

    // ---- Prologue: DMA tile 0 into buf 0, drain, barrier. ----
    STAGE(0, 0);
    asm volatile("s_waitcnt vmcnt(0)" ::: "memory");
    __builtin_amdgcn_s_barrier();
    asm volatile("" ::: "memory");

    for (int t = 0; t < NTILE; ++t) {
        f4* bufp = &tile[(t & 1) * TILE_F4];

        // (A) issue next tile's DMA into the other buffer NOW.
        if (t + 1 < NTILE) STAGE(t + 1, (t & 1) ^ 1);

        // (B) local scan of my 8 rows (channel ch); x kept in regs.
        f4 xcur[TSUB];
        const int r0 = sub * TSUB;
#pragma unroll
        for (int i = 0; i < TSUB; ++i) xcur[i] = bufp[swz(r0 + i, ch)];
        {
            f4 v = {0.f, 0.f, 0.f, 0.f};
#pragma unroll
            for (int i = 0; i < TSUB; ++i) v = fin4(a * v + bb * xcur[i]);
            pfx[sub * DG + ch] = v;
        }
        BAR();

        // (D) exclusive-prefix combine: thread ch (<8) walks the 64 subchunk
        // carries of its channel, 8-deep load-ahead; writes START states.
        if (tid < DG) {
            for (int s0 = 0; s0 < NSUB; s0 += 8) {
                f4 v0 = pfx[(s0 + 0) * DG + tid];
                f4 v1 = pfx[(s0 + 1) * DG + tid];
                f4 v2 = pfx[(s0 + 2) * DG + tid];
                f4 v3 = pfx[(s0 + 3) * DG + tid];
                f4 v4 = pfx[(s0 + 4) * DG + tid];
                f4 v5 = pfx[(s0 + 5) * DG + tid];
                f4 v6 = pfx[(s0 + 6) * DG + tid];
                f4 v7 = pfx[(s0 + 7) * DG + tid];
                pfx[(s0 + 0) * DG + tid] = S; S = fin4(a8 * S + v0);
                pfx[(s0 + 1) * DG + tid] = S; S = fin4(a8 * S + v1);
                pfx[(s0 + 2) * DG + tid] = S; S = fin4(a8 * S + v2);
                pfx[(s0 + 3) * DG + tid] = S; S = fin4(a8 * S + v3);
                pfx[(s0 + 4) * DG + tid] = S; S = fin4(a8 * S + v4);
                pfx[(s0 + 5) * DG + tid] = S; S = fin4(a8 * S + v5);
                pfx[(s0 + 6) * DG + tid] = S; S = fin4(a8 * S + v6);
                pfx[(s0 + 7) * DG + tid] = S; S = fin4(a8 * S + v7);
            }
        }
        BAR();

        // (E) rescan my rows from the corrected start state; y overwrites
        // the x-tile slots (x lives in xcur regs).
        {
            f4 s = pfx[sub * DG + ch];
#pragma unroll
            for (int i = 0; i < TSUB; ++i) {
                f4 xi = xcur[i];
                s = fin4(a * s + bb * xi);
                bufp[swz(r0 + i, ch)] = fin4(cc * s + dd * xi);
            }
        }
        BAR();

        // (F) cooperative y store: LINEAR LDS read (conflict-free burst),
        // inverse-swizzled global address (coalesced within 128B lines), NT.
#pragma unroll
        for (int q = 0; q < TSUB; ++q) {
            int sIdx = q * THREADS + tid;
            int row = sIdx >> 3;
            int col = ((sIdx & 7) - (sIdx >> 6)) & 7;
            f4 yv = bufp[sIdx];
            __builtin_nontemporal_store(
                yv, ybase + (size_t)(t * TTILE + row) * D4 + col);
        }

        // (G) counted wait: 8 newest outstanding VMEM = this tile's stores;
        // everything older (the DMA loads for t+1) must have retired.
        // Never drains to 0 -> stores stay in flight into the next tile.
        if (t + 1 < NTILE) {
            asm volatile("s_waitcnt vmcnt(8)" ::: "memory");
            __builtin_amdgcn_s_barrier();
            asm volatile("" ::: "memory");
        }
    }
#undef STAGE
}

extern "C" void kernel_launch(void* const* d_in, const int* in_sizes, int n_in,
                              void* d_out, int out_size, void* d_ws, size_t ws_size,
                              hipStream_t stream) {
    const float* x  = (const float*)d_in[0];
    const float* A  = (const float*)d_in[1];
    const float* B  = (const float*)d_in[2];
    const float* Cv = (const float*)d_in[3];
    const float* Dv = (const float*)d_in[4];
    float* y = (float*)d_out;

    const int nblocks = BATCHN * NDG;  // 256 blocks x 512 threads
    ssm_onepass<<<nblocks, THREADS, 0, stream>>>(x, A, B, Cv, Dv, y);
}

// Round 15
// 53.651 us; speedup vs baseline: 5.2176x; 1.0453x over previous
//
#include <hip/hip_runtime.h>

// x (4, 4096, 2048) f32; A,B,C,D (2048,) f32.  Single-kernel block-owned scan:
// each block owns (batch b, 8 f4-channels, ALL T). x read ONCE via
// double-buffered global_load_lds DMA (counted vmcnt, never drained to 0),
// y written once. Subchunk-carry combine is a hierarchical wave-parallel
// scan of affine pairs (R14's 8-thread serial chain was ~5 us of stall).
#define BATCHN  4
#define TLEN    4096
#define D4      512       // DMODEL/4 in f4 units
#define DG      8         // f4 channels per block
#define NDG     64        // D4/DG
#define THREADS 512
#define TTILE   512       // rows per LDS tile
#define NTILE   8         // TLEN/TTILE
#define NSUB    64        // THREADS/DG  (t-subchunks per tile)
#define TSUB    8         // TTILE/NSUB  (rows per thread)
#define TILE_F4 (TTILE * DG)  // 4096 f4 = 64 KiB per buffer

typedef float f4 __attribute__((ext_vector_type(4)));

// Saturating clamp to +-1e30 (survives fast-math; scrubs inf; identity for
// healthy channels). Proven R4-R14. Every affine-pair composition is clamped,
// so no inf is ever stored -> no 0*inf -> no nan anywhere.
__device__ __forceinline__ float fin(float v) {
    return fminf(fmaxf(v, -1.0e30f), 1.0e30f);
}
__device__ __forceinline__ f4 fin4(f4 v) {
    f4 r;
    r.x = fin(v.x); r.y = fin(v.y); r.z = fin(v.z); r.w = fin(v.w);
    return r;
}

// Affine map h -> p*h + v ; composition later(earlier(h)).
struct pr { f4 p, v; };
__device__ __forceinline__ pr comp(pr later, pr earlier) {
    pr r;
    r.p = fin4(later.p * earlier.p);
    r.v = fin4(later.p * earlier.v + later.v);
    return r;
}
__device__ __forceinline__ f4 shflup4(f4 x, int delta) {
    f4 r;
    r.x = __shfl_up(x.x, (unsigned)delta, 64);
    r.y = __shfl_up(x.y, (unsigned)delta, 64);
    r.z = __shfl_up(x.z, (unsigned)delta, 64);
    r.w = __shfl_up(x.w, (unsigned)delta, 64);
    return r;
}

// Raw barrier: lgkmcnt(0) for LDS visibility, NO vmcnt drain (keeps the
// DMA staging loads in flight across phases).
#define BAR() do { asm volatile("s_waitcnt lgkmcnt(0)" ::: "memory"); \
                   __builtin_amdgcn_s_barrier();                       \
                   asm volatile("" ::: "memory"); } while (0)

// LDS slot for logical (row, col): linear-in-lane DMA order, column rotated
// by (row>>3)&7 (rule #21: linear LDS dest + inverse-swizzled global source +
// swizzled read). Inverse: slot s holds x(row = s>>3, col = ((s&7)-(s>>6))&7).
__device__ __forceinline__ int swz(int row, int col) {
    return row * DG + ((col + (row >> 3)) & 7);
}

__global__ __launch_bounds__(THREADS, 1) void ssm_onepass(
    const float* __restrict__ xg, const float* __restrict__ A,
    const float* __restrict__ B, const float* __restrict__ Cv,
    const float* __restrict__ Dv, float* __restrict__ yg) {
    __shared__ f4 tile[2 * TILE_F4];  // 128 KiB double buffer
    __shared__ f4 wpP[NSUB];          // wave-partial / exclusive-prefix p
    __shared__ f4 wpV[NSUB];          // and v   (8 waves x 8 ch)
    __shared__ f4 totP[DG], totV[DG]; // tile-total pair per channel

    const int tid  = threadIdx.x;
    const int lane = tid & 63;
    const int wid  = tid >> 6;        // wave 0..7
    const int dg   = blockIdx.x & (NDG - 1);
    const int b    = blockIdx.x >> 6;
    const int ch   = tid & (DG - 1);  // my f4 channel within the group
    const int sub  = tid >> 3;        // my t-subchunk (0..63)
    const int siw  = (lane >> 3);     // sub index within my wave (0..7)

    const int d4 = dg * DG + ch;
    const f4 a  = ((const f4*)A)[d4];
    const f4 bb = ((const f4*)B)[d4];
    const f4 cc = ((const f4*)Cv)[d4];
    const f4 dd = ((const f4*)Dv)[d4];
    const f4 a2 = fin4(a * a), a4 = fin4(a2 * a2), a8 = fin4(a4 * a4);
    const f4 ONE = {1.f, 1.f, 1.f, 1.f};
    const f4 ZERO = {0.f, 0.f, 0.f, 0.f};

    f4 S = ZERO;  // tile-running state, maintained redundantly in ALL threads

    const size_t slice = (size_t)b * TLEN * D4 + (size_t)dg * DG;  // f4 units
    const f4* xbase = (const f4*)xg + slice;
    f4* ybase = (f4*)yg + slice;

    // Per-thread DMA descriptor (inverse-swizzled global source).
    int g_row[TSUB], g_col[TSUB];
#pragma unroll
    for (int q = 0; q < TSUB; ++q) {
        int s = q * THREADS + wid * 64 + lane;
        g_row[q] = s >> 3;
        g_col[q] = ((s & 7) - (s >> 6)) & 7;
    }

#define STAGE(t_, bufi_) do {                                                  \
        const f4* gq;                                                          \
        f4* lq;                                                                \
        _Pragma("unroll")                                                      \
        for (int q = 0; q < TSUB; ++q) {                                       \
            gq = xbase + (size_t)((t_) * TTILE + g_row[q]) * D4 + g_col[q];    \
            lq = &tile[(bufi_) * TILE_F4 + q * THREADS + wid * 64];            \
            __builtin_amdgcn_global_load_lds(                                  \
                (const __attribute__((address_space(1))) void*)gq,             \
                (__attribute__((address_space(3))) void*)lq, 16, 0, 0);        \
        }                                                                      \
    } while (0)

    // ---- Prologue: DMA tile 0 into buf 0, drain, barrier. ----
    STAGE(0, 0);
    asm volatile("s_waitcnt vmcnt(0)" ::: "memory");
    __builtin_amdgcn_s_barrier();
    asm volatile("" ::: "memory");

    for (int t = 0; t < NTILE; ++t) {
        f4* bufp = &tile[(t & 1) * TILE_F4];

        // (A) issue next tile's DMA into the other buffer NOW.
        if (t + 1 < NTILE) STAGE(t + 1, (t & 1) ^ 1);

        // (B) local scan of my 8 rows (channel ch); x kept in regs.
        f4 xcur[TSUB];
        const int r0 = sub * TSUB;
#pragma unroll
        for (int i = 0; i < TSUB; ++i) xcur[i] = bufp[swz(r0 + i, ch)];
        pr me;
        {
            f4 v = ZERO;
#pragma unroll
            for (int i = 0; i < TSUB; ++i) v = fin4(a * v + bb * xcur[i]);
            me.p = a8; me.v = v;   // my subchunk's affine map
        }

        // (B2) in-wave Kogge-Stone inclusive scan over the 8 subs (shuffles).
#pragma unroll
        for (int d = 1; d <= 4; d <<= 1) {
            pr up;
            up.p = shflup4(me.p, 8 * d);
            up.v = shflup4(me.v, 8 * d);
            if (siw >= d) me = comp(me, up);
        }
        if (siw == 7) { wpP[wid * DG + ch] = me.p; wpV[wid * DG + ch] = me.v; }
        BAR();

        // (B3) wave 0 scans the 8 wave-partials per channel; writes exclusive
        // prefixes back and the tile total.
        if (tid < 64) {
            const int ww = tid >> 3, c2 = tid & 7;
            pr q; q.p = wpP[tid]; q.v = wpV[tid];
#pragma unroll
            for (int d = 1; d <= 4; d <<= 1) {
                pr up;
                up.p = shflup4(q.p, 8 * d);
                up.v = shflup4(q.v, 8 * d);
                if (ww >= d) q = comp(q, up);
            }
            if (ww == 7) { totP[c2] = q.p; totV[c2] = q.v; }
            pr ex;
            ex.p = shflup4(q.p, 8);
            ex.v = shflup4(q.v, 8);
            if (ww == 0) { ex.p = ONE; ex.v = ZERO; }
            wpP[tid] = ex.p; wpV[tid] = ex.v;
        }
        BAR();

        // (B4) my exclusive start state: (within-wave exclusive) ∘ (wave
        // exclusive), applied to S.
        pr wex; wex.p = wpP[wid * DG + ch]; wex.v = wpV[wid * DG + ch];
        pr mex;
        mex.p = shflup4(me.p, 8);
        mex.v = shflup4(me.v, 8);
        if (siw == 0) { mex.p = ONE; mex.v = ZERO; }
        pr st = comp(mex, wex);
        f4 s = fin4(fin4(st.p * S) + st.v);

        // advance S by the tile total (all threads, consistent per channel).
        S = fin4(fin4(totP[ch] * S) + totV[ch]);

        // (E) rescan my rows from s; y overwrites the x-tile slots.
#pragma unroll
        for (int i = 0; i < TSUB; ++i) {
            f4 xi = xcur[i];
            s = fin4(a * s + bb * xi);
            bufp[swz(r0 + i, ch)] = fin4(cc * s + dd * xi);
        }
        BAR();

        // (F) cooperative y store: LINEAR LDS read, inverse-swizzled global
        // address (coalesced within each row's 128B line), non-temporal.
#pragma unroll
        for (int q = 0; q < TSUB; ++q) {
            int sIdx = q * THREADS + tid;
            int row = sIdx >> 3;
            int col = ((sIdx & 7) - (sIdx >> 6)) & 7;
            f4 yv = bufp[sIdx];
            __builtin_nontemporal_store(
                yv, ybase + (size_t)(t * TTILE + row) * D4 + col);
        }

        // (G) counted wait: 8 newest outstanding VMEM = this tile's stores;
        // everything older (the t+1 DMA loads) has retired. Never drain to 0.
        if (t + 1 < NTILE) {
            asm volatile("s_waitcnt vmcnt(8)" ::: "memory");
            __builtin_amdgcn_s_barrier();
            asm volatile("" ::: "memory");
        }
    }
#undef STAGE
}

extern "C" void kernel_launch(void* const* d_in, const int* in_sizes, int n_in,
                              void* d_out, int out_size, void* d_ws, size_t ws_size,
                              hipStream_t stream) {
    const float* x  = (const float*)d_in[0];
    const float* A  = (const float*)d_in[1];
    const float* B  = (const float*)d_in[2];
    const float* Cv = (const float*)d_in[3];
    const float* Dv = (const float*)d_in[4];
    float* y = (float*)d_out;

    const int nblocks = BATCHN * NDG;  // 256 blocks x 512 threads
    ssm_onepass<<<nblocks, THREADS, 0, stream>>>(x, A, B, Cv, Dv, y);
}

// Round 16
// 45.691 us; speedup vs baseline: 6.1265x; 1.1742x over previous
//
#include <hip/hip_runtime.h>

// x (4, 4096, 2048) f32; A,B,C,D (2048,) f32.  Single-kernel block-owned scan,
// DIRECT-REGISTER form: each block owns (batch b, 8 f4-channels, ALL T).
// Key insight vs R13-R15: in the compute layout, 8 same-sub lanes cover
// ch 0..7 of one row = 128 B contiguous = one HBM granule. So direct global
// loads/stores are already full-efficiency -- the LDS transpose pipeline
// (DMA staging, swizzle, y round-trip, extra barriers) bought nothing.
// LDS now holds only the 4.5 KB prefix-exchange arrays.
#define BATCHN  4
#define TLEN    4096
#define D4      512       // DMODEL/4 in f4 units
#define DG      8         // f4 channels per block
#define NDG     64        // D4/DG
#define THREADS 512
#define TTILE   512       // rows per tile
#define NTILE   8         // TLEN/TTILE
#define NSUB    64        // THREADS/DG  (t-subchunks per tile)
#define TSUB    8         // TTILE/NSUB  (rows per thread)

typedef float f4 __attribute__((ext_vector_type(4)));

// Saturating clamp to +-1e30 (survives fast-math; scrubs inf; identity for
// healthy channels). Proven R4-R15. Every composition is clamped, so no inf
// is ever stored -> no 0*inf -> no nan anywhere.
__device__ __forceinline__ float fin(float v) {
    return fminf(fmaxf(v, -1.0e30f), 1.0e30f);
}
__device__ __forceinline__ f4 fin4(f4 v) {
    f4 r;
    r.x = fin(v.x); r.y = fin(v.y); r.z = fin(v.z); r.w = fin(v.w);
    return r;
}

// Affine map h -> p*h + v ; composition later(earlier(h)).
struct pr { f4 p, v; };
__device__ __forceinline__ pr comp(pr later, pr earlier) {
    pr r;
    r.p = fin4(later.p * earlier.p);
    r.v = fin4(later.p * earlier.v + later.v);
    return r;
}
__device__ __forceinline__ f4 shflup4(f4 x, int delta) {
    f4 r;
    r.x = __shfl_up(x.x, (unsigned)delta, 64);
    r.y = __shfl_up(x.y, (unsigned)delta, 64);
    r.z = __shfl_up(x.z, (unsigned)delta, 64);
    r.w = __shfl_up(x.w, (unsigned)delta, 64);
    return r;
}

// Raw barrier: lgkmcnt(0) for LDS visibility, NO vmcnt drain (keeps the
// xnext prefetch loads and y stores in flight across phases).
#define BAR() do { asm volatile("s_waitcnt lgkmcnt(0)" ::: "memory"); \
                   __builtin_amdgcn_s_barrier();                       \
                   asm volatile("" ::: "memory"); } while (0)

__global__ __launch_bounds__(THREADS) void ssm_direct(
    const float* __restrict__ xg, const float* __restrict__ A,
    const float* __restrict__ B, const float* __restrict__ Cv,
    const float* __restrict__ Dv, float* __restrict__ yg) {
    // Double-buffered (by t&1) prefix-exchange arrays; ~4.5 KB total.
    __shared__ f4 wpP[2][NSUB], wpV[2][NSUB];
    __shared__ f4 totP[2][DG], totV[2][DG];

    const int tid  = threadIdx.x;
    const int lane = tid & 63;
    const int wid  = tid >> 6;        // wave 0..7
    const int dg   = blockIdx.x & (NDG - 1);
    const int b    = blockIdx.x >> 6;
    const int ch   = tid & (DG - 1);  // my f4 channel within the group
    const int sub  = tid >> 3;        // my t-subchunk (0..63)
    const int siw  = (lane >> 3);     // sub index within my wave (0..7)

    const int d4 = dg * DG + ch;
    const f4 a  = ((const f4*)A)[d4];
    const f4 bb = ((const f4*)B)[d4];
    const f4 cc = ((const f4*)Cv)[d4];
    const f4 dd = ((const f4*)Dv)[d4];
    const f4 a2 = fin4(a * a), a4 = fin4(a2 * a2), a8 = fin4(a4 * a4);
    const f4 ONE = {1.f, 1.f, 1.f, 1.f};
    const f4 ZERO = {0.f, 0.f, 0.f, 0.f};

    f4 S = ZERO;  // tile-running state, maintained redundantly in ALL threads

    // My row pointer: row (t*TTILE + sub*TSUB + i), channel ch.
    const size_t slice = (size_t)b * TLEN * D4 + (size_t)dg * DG + ch;
    const f4* xp = (const f4*)xg + slice + (size_t)sub * TSUB * D4;
    f4* yp = (f4*)yg + slice + (size_t)sub * TSUB * D4;

    // ---- Prologue: load tile 0 directly into registers. ----
    f4 xcur[TSUB], xnext[TSUB];
#pragma unroll
    for (int i = 0; i < TSUB; ++i) xcur[i] = xp[(size_t)i * D4];

    for (int t = 0; t < NTILE; ++t) {
        const int pb = t & 1;

        // (A) issue next tile's loads NOW; consumed at the rotate below.
        // They fly under the scan + barriers (HBM latency hidden).
        if (t + 1 < NTILE) {
            const f4* xn = xp + (size_t)(t + 1) * TTILE * D4;
#pragma unroll
            for (int i = 0; i < TSUB; ++i) xnext[i] = xn[(size_t)i * D4];
        }

        // (B) local scan of my 8 rows -> my subchunk's affine map (a8, v).
        pr me;
        {
            f4 v = ZERO;
#pragma unroll
            for (int i = 0; i < TSUB; ++i) v = fin4(a * v + bb * xcur[i]);
            me.p = a8; me.v = v;
        }

        // (B2) in-wave Kogge-Stone inclusive scan over the 8 subs (shuffles).
#pragma unroll
        for (int d = 1; d <= 4; d <<= 1) {
            pr up;
            up.p = shflup4(me.p, 8 * d);
            up.v = shflup4(me.v, 8 * d);
            if (siw >= d) me = comp(me, up);
        }
        if (siw == 7) { wpP[pb][wid * DG + ch] = me.p; wpV[pb][wid * DG + ch] = me.v; }
        BAR();

        // (B3) wave 0 scans the 8 wave-partials per channel; writes exclusive
        // prefixes back and the tile-total pair.
        if (tid < 64) {
            const int ww = tid >> 3, c2 = tid & 7;
            pr q; q.p = wpP[pb][tid]; q.v = wpV[pb][tid];
#pragma unroll
            for (int d = 1; d <= 4; d <<= 1) {
                pr up;
                up.p = shflup4(q.p, 8 * d);
                up.v = shflup4(q.v, 8 * d);
                if (ww >= d) q = comp(q, up);
            }
            if (ww == 7) { totP[pb][c2] = q.p; totV[pb][c2] = q.v; }
            pr ex;
            ex.p = shflup4(q.p, 8);
            ex.v = shflup4(q.v, 8);
            if (ww == 0) { ex.p = ONE; ex.v = ZERO; }
            wpP[pb][tid] = ex.p; wpV[pb][tid] = ex.v;
        }
        BAR();

        // (B4) my exclusive start state = (within-wave excl) ∘ (wave excl),
        // applied to the running state S.
        pr wex; wex.p = wpP[pb][wid * DG + ch]; wex.v = wpV[pb][wid * DG + ch];
        pr mex;
        mex.p = shflup4(me.p, 8);
        mex.v = shflup4(me.v, 8);
        if (siw == 0) { mex.p = ONE; mex.v = ZERO; }
        pr st = comp(mex, wex);
        f4 s = fin4(fin4(st.p * S) + st.v);

        // advance S by the tile total (all threads, consistent per channel).
        S = fin4(fin4(totP[pb][ch] * S) + totV[pb][ch]);

        // (E) rescan my rows from s; store y DIRECTLY from registers
        // (8 same-sub lanes x 16B = 128B contiguous per row), non-temporal.
        f4* yt = yp + (size_t)t * TTILE * D4;
#pragma unroll
        for (int i = 0; i < TSUB; ++i) {
            f4 xi = xcur[i];
            s = fin4(a * s + bb * xi);
            f4 yv = fin4(cc * s + dd * xi);
            __builtin_nontemporal_store(yv, yt + (size_t)i * D4);
        }

        // rotate prefetched tile into xcur (reg-reg; compiler places the
        // precise vmcnt wait for xnext here).
        if (t + 1 < NTILE) {
#pragma unroll
            for (int i = 0; i < TSUB; ++i) xcur[i] = xnext[i];
        }
    }
}

extern "C" void kernel_launch(void* const* d_in, const int* in_sizes, int n_in,
                              void* d_out, int out_size, void* d_ws, size_t ws_size,
                              hipStream_t stream) {
    const float* x  = (const float*)d_in[0];
    const float* A  = (const float*)d_in[1];
    const float* B  = (const float*)d_in[2];
    const float* Cv = (const float*)d_in[3];
    const float* Dv = (const float*)d_in[4];
    float* y = (float*)d_out;

    const int nblocks = BATCHN * NDG;  // 256 blocks x 512 threads
    ssm_direct<<<nblocks, THREADS, 0, stream>>>(x, A, B, Cv, Dv, y);
}